// Round 2
// baseline (212.277 us; speedup 1.0000x reference)
//
#include <hip/hip_runtime.h>

// 4 atoms per thread: all sequential traffic becomes float4/int4 (16B/lane).
// Gathers (coords[z/x/y]) remain scalar dword loads, mostly L3-resident.

__device__ __forceinline__ float3 nrm3(float ax, float ay, float az) {
    float s = ax * ax + ay * ay + az * az;
    float r = 1.0f / sqrtf(s);
    return make_float3(ax * r, ay * r, az * r);
}

// Compute rotation rows R[0..2]=x, R[3..5]=y, R[6..8]=z for one atom.
__device__ __forceinline__ void rot_matrix(
    int t, float cx, float cy, float cz,
    int zi, int xi, int yi,
    const float* __restrict__ coords,
    float R[9])
{
    if (t == 5) {
        R[0] = 1.0f; R[1] = 0.0f; R[2] = 0.0f;
        R[3] = 0.0f; R[4] = 1.0f; R[5] = 0.0f;
        R[6] = 0.0f; R[7] = 0.0f; R[8] = 1.0f;
        return;
    }

    float3 zv = nrm3(coords[3 * zi + 0] - cx,
                     coords[3 * zi + 1] - cy,
                     coords[3 * zi + 2] - cz);

    float3 xv;
    if (t == 4) {
        xv = make_float3(1.0f - zv.x, zv.x, 0.0f);
    } else {
        xv = nrm3(coords[3 * xi + 0] - cx,
                  coords[3 * xi + 1] - cy,
                  coords[3 * xi + 2] - cz);
    }

    if (t == 1) {
        zv = nrm3(zv.x + xv.x, zv.y + xv.y, zv.z + xv.z);
    }

    if (t == 2 || t == 3) {
        float3 yn = nrm3(coords[3 * yi + 0] - cx,
                         coords[3 * yi + 1] - cy,
                         coords[3 * yi + 2] - cz);
        if (t == 2) {
            xv = nrm3(xv.x + yn.x, xv.y + yn.y, xv.z + yn.z);
        } else {
            zv = nrm3(zv.x + xv.x + yn.x, zv.y + xv.y + yn.y, zv.z + xv.z + yn.z);
        }
    }

    float dzx = zv.x * xv.x + zv.y * xv.y + zv.z * xv.z;
    xv = nrm3(xv.x - zv.x * dzx, xv.y - zv.y * dzx, xv.z - zv.z * dzx);

    float3 yv = make_float3(zv.y * xv.z - zv.z * xv.y,
                            zv.z * xv.x - zv.x * xv.z,
                            zv.x * xv.y - zv.y * xv.x);

    R[0] = xv.x; R[1] = xv.y; R[2] = xv.z;
    R[3] = yv.x; R[4] = yv.y; R[5] = yv.z;
    R[6] = zv.x; R[7] = zv.y; R[8] = zv.z;
}

__device__ __forceinline__ void apply_rot(
    const float R[9], const float dp[3], const float Q[9],
    float od[3], float oq[9])
{
    // d[j] = sum_k dp[k] * R[k*3+j]
    od[0] = dp[0] * R[0] + dp[1] * R[3] + dp[2] * R[6];
    od[1] = dp[0] * R[1] + dp[1] * R[4] + dp[2] * R[7];
    od[2] = dp[0] * R[2] + dp[1] * R[5] + dp[2] * R[8];

    // M = R^T * Q : M[a][l] = sum_k R[k*3+a] * Q[k*3+l]
    float M[9];
#pragma unroll
    for (int a = 0; a < 3; ++a) {
#pragma unroll
        for (int l = 0; l < 3; ++l) {
            M[a * 3 + l] = R[0 * 3 + a] * Q[0 * 3 + l]
                         + R[1 * 3 + a] * Q[1 * 3 + l]
                         + R[2 * 3 + a] * Q[2 * 3 + l];
        }
    }
    // O = M * R : O[a][b] = sum_l M[a][l] * R[l*3+b]
#pragma unroll
    for (int a = 0; a < 3; ++a) {
#pragma unroll
        for (int b = 0; b < 3; ++b) {
            oq[a * 3 + b] = M[a * 3 + 0] * R[0 * 3 + b]
                          + M[a * 3 + 1] * R[1 * 3 + b]
                          + M[a * 3 + 2] * R[2 * 3 + b];
        }
    }
}

__global__ __launch_bounds__(256) void mp_rot4_kernel(
    const float* __restrict__ coords,
    const int* __restrict__ za,
    const int* __restrict__ xa,
    const int* __restrict__ ya,
    const int* __restrict__ at,
    const float* __restrict__ dip,
    const float* __restrict__ quad,
    float* __restrict__ out_d,
    float* __restrict__ out_q,
    int ngroups, int n)
{
    int g = blockIdx.x * blockDim.x + threadIdx.x;
    if (g >= ngroups) return;
    int base = 4 * g;

    if (base + 4 <= n) {
        // ---- fully vectorized path: 4 consecutive atoms ----
        float4 cA = ((const float4*)coords)[3 * g + 0];
        float4 cB = ((const float4*)coords)[3 * g + 1];
        float4 cC = ((const float4*)coords)[3 * g + 2];
        float c[12] = {cA.x, cA.y, cA.z, cA.w, cB.x, cB.y, cB.z, cB.w,
                       cC.x, cC.y, cC.z, cC.w};

        float4 dA = ((const float4*)dip)[3 * g + 0];
        float4 dB = ((const float4*)dip)[3 * g + 1];
        float4 dC = ((const float4*)dip)[3 * g + 2];
        float dp[12] = {dA.x, dA.y, dA.z, dA.w, dB.x, dB.y, dB.z, dB.w,
                        dC.x, dC.y, dC.z, dC.w};

        float q[36];
#pragma unroll
        for (int k = 0; k < 9; ++k) {
            float4 v = ((const float4*)quad)[9 * g + k];
            q[4 * k + 0] = v.x; q[4 * k + 1] = v.y;
            q[4 * k + 2] = v.z; q[4 * k + 3] = v.w;
        }

        int4 z4 = ((const int4*)za)[g];
        int4 x4 = ((const int4*)xa)[g];
        int4 y4 = ((const int4*)ya)[g];
        int4 t4 = ((const int4*)at)[g];
        int zi[4] = {z4.x, z4.y, z4.z, z4.w};
        int xi[4] = {x4.x, x4.y, x4.z, x4.w};
        int yi[4] = {y4.x, y4.y, y4.z, y4.w};
        int ti[4] = {t4.x, t4.y, t4.z, t4.w};

        float od[12], oq[36];
#pragma unroll
        for (int a = 0; a < 4; ++a) {
            float R[9];
            rot_matrix(ti[a], c[3 * a + 0], c[3 * a + 1], c[3 * a + 2],
                       zi[a], xi[a], yi[a], coords, R);
            apply_rot(R, &dp[3 * a], &q[9 * a], &od[3 * a], &oq[9 * a]);
        }

        ((float4*)out_d)[3 * g + 0] = make_float4(od[0], od[1], od[2], od[3]);
        ((float4*)out_d)[3 * g + 1] = make_float4(od[4], od[5], od[6], od[7]);
        ((float4*)out_d)[3 * g + 2] = make_float4(od[8], od[9], od[10], od[11]);
#pragma unroll
        for (int k = 0; k < 9; ++k) {
            ((float4*)out_q)[9 * g + k] =
                make_float4(oq[4 * k + 0], oq[4 * k + 1],
                            oq[4 * k + 2], oq[4 * k + 3]);
        }
    } else {
        // ---- tail: scalar per-atom fallback ----
        for (int i = base; i < n; ++i) {
            float R[9];
            rot_matrix(at[i], coords[3 * i + 0], coords[3 * i + 1],
                       coords[3 * i + 2], za[i], xa[i], ya[i], coords, R);
            float dpl[3] = {dip[3 * i + 0], dip[3 * i + 1], dip[3 * i + 2]};
            float Q[9];
#pragma unroll
            for (int k = 0; k < 9; ++k) Q[k] = quad[9 * i + k];
            float od[3], oq[9];
            apply_rot(R, dpl, Q, od, oq);
#pragma unroll
            for (int k = 0; k < 3; ++k) out_d[3 * i + k] = od[k];
#pragma unroll
            for (int k = 0; k < 9; ++k) out_q[9 * i + k] = oq[k];
        }
    }
}

extern "C" void kernel_launch(void* const* d_in, const int* in_sizes, int n_in,
                              void* d_out, int out_size, void* d_ws, size_t ws_size,
                              hipStream_t stream) {
    const float* coords = (const float*)d_in[0];
    const int* za = (const int*)d_in[1];
    const int* xa = (const int*)d_in[2];
    const int* ya = (const int*)d_in[3];
    const int* at = (const int*)d_in[4];
    const float* dip = (const float*)d_in[5];
    const float* quad = (const float*)d_in[6];

    int n = in_sizes[1];  // z_atoms count == N
    float* out_d = (float*)d_out;
    float* out_q = out_d + (size_t)3 * n;

    int ngroups = (n + 3) / 4;
    int block = 256;
    int grid = (ngroups + block - 1) / block;
    mp_rot4_kernel<<<grid, block, 0, stream>>>(coords, za, xa, ya, at, dip, quad,
                                               out_d, out_q, ngroups, n);
}